// Round 4
// baseline (133.749 us; speedup 1.0000x reference)
//
#include <hip/hip_runtime.h>
#include <hip/hip_bf16.h>

typedef __bf16 bf16_t;
typedef __bf16 bf16x8 __attribute__((ext_vector_type(8)));
typedef float f32x4 __attribute__((ext_vector_type(4)));
typedef unsigned short u16;
typedef unsigned int u32;
typedef unsigned long long u64;

#define CH    128
#define NTOK  4096
#define DIMH  32

__device__ __forceinline__ float fast_exp2(float x) {
#if __has_builtin(__builtin_amdgcn_exp2f)
  return __builtin_amdgcn_exp2f(x);
#else
  return exp2f(x);
#endif
}

// ===================== Kernel A: QKV projection =====================
// x: [B][128][4096] f32, w: [384][128] f32.
// qs/ks: [bh][n][32] bf16 (q pre-scaled by 32^-0.5*log2e).
// vs: TILED+SWIZZLED [bh][jb][32 d][64 j] bf16, 16B-chunk index within each
//     128B d-row XORed with (d&7) so attention's LDS V-frag reads are
//     bank-conflict-free (linear 128B rows would be a 16-way conflict).
__global__ __launch_bounds__(256)
void qkv_proj(const float* __restrict__ x, const float* __restrict__ w,
              bf16_t* __restrict__ qs, bf16_t* __restrict__ ks, bf16_t* __restrict__ vs)
{
  __shared__ float xs[128][64];
  __shared__ float wt[128][64];
  const int tid = threadIdx.x;
  const int n0 = blockIdx.x * 64;
  const int o0 = blockIdx.y * 64;
  const int b  = blockIdx.z;

  { // stage x tile [128 c][64 n] via float4 (coalesced)
    const float* xb = x + ((size_t)b * CH) * NTOK + n0;
    const int f4 = tid & 15, c0 = tid >> 4;
    #pragma unroll
    for (int p = 0; p < 8; ++p) {
      const int c = p * 16 + c0;
      *(float4*)&xs[c][f4 * 4] = *(const float4*)(xb + (size_t)c * NTOK + f4 * 4);
    }
  }
  { // stage w tile transposed: wt[c][o_local]
    const int o_l = tid & 63, q4 = tid >> 6;
    const float* wrow = w + (size_t)(o0 + o_l) * CH;
    #pragma unroll
    for (int p = 0; p < 8; ++p) {
      const int c4 = p * 4 + q4;
      const float4 v4 = *(const float4*)(wrow + c4 * 4);
      wt[c4*4+0][o_l] = v4.x;
      wt[c4*4+1][o_l] = v4.y;
      wt[c4*4+2][o_l] = v4.z;
      wt[c4*4+3][o_l] = v4.w;
    }
  }
  __syncthreads();

  const int tx = tid & 15, ty = tid >> 4;
  float acc[4][4] = {};
  for (int c = 0; c < 128; ++c) {
    const float4 xv = *(const float4*)&xs[c][tx * 4];
    const float4 wv = *(const float4*)&wt[c][ty * 4];
    const float xa[4] = {xv.x, xv.y, xv.z, xv.w};
    const float wa[4] = {wv.x, wv.y, wv.z, wv.w};
    #pragma unroll
    for (int io = 0; io < 4; ++io)
      #pragma unroll
      for (int in = 0; in < 4; ++in)
        acc[io][in] += wa[io] * xa[in];
  }
  __syncthreads();

  float (*out_s)[65] = (float(*)[65])&xs[0][0];
  #pragma unroll
  for (int io = 0; io < 4; ++io)
    #pragma unroll
    for (int in = 0; in < 4; ++in)
      out_s[ty*4+io][tx*4+in] = acc[io][in];
  __syncthreads();

  const float QSCALE = 0.17677669529663687f * 1.4426950408889634f; // 32^-0.5 * log2(e)
  if (o0 < 256) {
    bf16_t* dst = (o0 < 128) ? qs : ks;
    const float mul = (o0 < 128) ? QSCALE : 1.0f;
    const int obase = o0 & 127;
    #pragma unroll
    for (int p = 0; p < 16; ++p) {
      const int n_l = p * 4 + (tid >> 6);
      const int o_l = tid & 63;
      const int o = obase + o_l;
      const int h = o >> 5, d = o & 31;
      dst[(((size_t)(b*4 + h)) * NTOK + n0 + n_l) * DIMH + d] = (bf16_t)(out_s[o_l][n_l] * mul);
    }
  } else {
    // v tiled+swizzled: tile (b*4+h, jb=n0/64); elem = d*64 + ((jc^(d&7))*8 + e)
    const int obase = o0 - 256;
    const int jb = n0 >> 6;
    #pragma unroll
    for (int p = 0; p < 16; ++p) {
      const int o_l = p * 4 + (tid >> 6);
      const int n_l = tid & 63;
      const int o = obase + o_l;
      const int h = o >> 5, d = o & 31;
      const int jc = n_l >> 3, e = n_l & 7;
      const size_t tilebase = ((size_t)(b*4 + h) * 64 + jb) * 2048;
      vs[tilebase + d*64 + ((jc ^ (d & 7)) * 8) + e] = (bf16_t)out_s[o_l][n_l];
    }
  }
}

// helper: stage one 4KB K-tile + 4KB V-tile into LDS (direct-to-LDS, no VGPR round trip)
__device__ __forceinline__ void stage_tile(const char* kg, const char* vg,
                                           char* lds, int tid)
{
#if __has_builtin(__builtin_amdgcn_global_load_lds)
  __builtin_amdgcn_global_load_lds(
      (const __attribute__((address_space(1))) void*)(kg + tid * 16),
      (__attribute__((address_space(3))) void*)(lds + tid * 16), 16, 0, 0);
  __builtin_amdgcn_global_load_lds(
      (const __attribute__((address_space(1))) void*)(vg + tid * 16),
      (__attribute__((address_space(3))) void*)(lds + 4096 + tid * 16), 16, 0, 0);
#else
  const uint4 a = *(const uint4*)(kg + tid * 16);
  const uint4 b = *(const uint4*)(vg + tid * 16);
  *(uint4*)(lds + tid * 16) = a;
  *(uint4*)(lds + 4096 + tid * 16) = b;
#endif
}

// ===================== Kernel B: flash attention (LDS-staged, 64 i/wave) =====================
// Block: 4 waves x 64 i = 256 i-rows; per j-iter the block stages the 64j K-tile
// (4KB, [64][32] bf16) + V-tile (4KB, swizzled [32][64]) into LDS double-buffer;
// every wave computes 4 Q-chunks (q=0..3) against the shared tiles:
//   S^T = mfma(K, Q_q)  -> online softmax per q -> P bounce via LDS -> O^T += mfma(V^T, P_q)
// One barrier per iter; staging loads stay in flight across the compute phase.
template<int JB_PER>
__global__ __launch_bounds__(256, 2)
void attn_fwd(const bf16_t* __restrict__ qs, const bf16_t* __restrict__ ks,
              const bf16_t* __restrict__ vs, float* __restrict__ Apart,
              float* __restrict__ ml)
{
  __shared__ alignas(16) char kvbuf[2][8192];          // [buf][K 4KB | V 4KB]
  __shared__ alignas(16) u32  pbuf[4][4][16][36];      // [wave][q][i-row][32 u32 + pad], 144B rows

  const int bh    = blockIdx.x;   // 0..7 (fastest dim -> one head per XCD)
  const int ic    = blockIdx.y;   // 0..15
  const int split = blockIdx.z;
  const int tid   = threadIdx.x;
  const int wv    = tid >> 6;
  const int lane  = tid & 63;
  const int g = lane >> 4, r = lane & 15;
  const int i_base = ic * 256 + wv * 64;

  const bf16_t* qh = qs + (size_t)bh * NTOK * DIMH;
  const char*   kg = (const char*)(ks + (size_t)bh * NTOK * DIMH);
  const char*   vg = (const char*)(vs + (size_t)bh * NTOK * DIMH);

  // Q B-frags (hoisted): col=i (lane&15), k=d ((lane>>4)*8+e)
  bf16x8 qf[4];
  #pragma unroll
  for (int q = 0; q < 4; ++q)
    qf[q] = *(const bf16x8*)(qh + (size_t)(i_base + 16*q + r) * DIMH + g * 8);

  f32x4 accL[4] = {}, accH[4] = {};
  const f32x4 zero = {0.f, 0.f, 0.f, 0.f};
  float mrun[4] = {-3.0e38f, -3.0e38f, -3.0e38f, -3.0e38f};
  float lrun[4] = {0.f, 0.f, 0.f, 0.f};

  const int jb0 = split * JB_PER;
  stage_tile(kg + (size_t)jb0 * 4096, vg + (size_t)jb0 * 4096, kvbuf[0], tid);

  int buf = 0;
  for (int it = 0; it < JB_PER; ++it) {
    // staged data for `buf` ready + all waves past previous compute
    asm volatile("s_waitcnt vmcnt(0) lgkmcnt(0)" ::: "memory");
    __builtin_amdgcn_s_barrier();

    const char* kb = kvbuf[buf];
    const char* vb = kvbuf[buf] + 4096;

    // ---- LDS -> frag reads ----
    bf16x8 kf[4], vlo[2], vhi[2];
    #pragma unroll
    for (int t = 0; t < 4; ++t)
      kf[t] = __builtin_bit_cast(bf16x8, *(const uint4*)(kb + (16*t + r) * 64 + g * 16));
    #pragma unroll
    for (int c = 0; c < 2; ++c) {
      const int swz = ((4*c + g) ^ (r & 7)) * 16;
      vlo[c] = __builtin_bit_cast(bf16x8, *(const uint4*)(vb + r * 128 + swz));
      vhi[c] = __builtin_bit_cast(bf16x8, *(const uint4*)(vb + (16 + r) * 128 + swz));
    }

    // ---- QK^T: 16 MFMAs, st[t][q] = S^T[j=16t+4g+u][i=i_base+16q+r] ----
    f32x4 st[4][4];
    #pragma unroll
    for (int t = 0; t < 4; ++t)
      #pragma unroll
      for (int q = 0; q < 4; ++q)
        st[t][q] = __builtin_amdgcn_mfma_f32_16x16x32_bf16(kf[t], qf[q], zero, 0, 0, 0);

    // ---- stage next tile (loads stay in flight through the rest of the iter) ----
    if (it + 1 < JB_PER) {
      const size_t off = (size_t)(jb0 + it + 1) * 4096;
      stage_tile(kg + off, vg + off, kvbuf[buf ^ 1], tid);
    }

    // ---- online softmax per q (defer-max THR=8) ----
    u32 pk0[4][4], pk1[4][4];
    #pragma unroll
    for (int q = 0; q < 4; ++q) {
      float m = -3.0e38f;
      #pragma unroll
      for (int t = 0; t < 4; ++t)
        m = fmaxf(m, fmaxf(fmaxf(st[t][q][0], st[t][q][1]),
                           fmaxf(st[t][q][2], st[t][q][3])));
      m = fmaxf(m, __shfl_xor(m, 16));
      m = fmaxf(m, __shfl_xor(m, 32));
      const bool skip = __all(m - mrun[q] <= 8.0f);
      const float m_new = skip ? mrun[q] : fmaxf(mrun[q], m);
      float ps = 0.f;
      #pragma unroll
      for (int t = 0; t < 4; ++t) {
        const float p0 = fast_exp2(st[t][q][0] - m_new);
        const float p1 = fast_exp2(st[t][q][1] - m_new);
        const float p2 = fast_exp2(st[t][q][2] - m_new);
        const float p3 = fast_exp2(st[t][q][3] - m_new);
        ps += (p0 + p1) + (p2 + p3);
        const u16 b0 = __builtin_bit_cast(u16, (__bf16)p0);
        const u16 b1 = __builtin_bit_cast(u16, (__bf16)p1);
        const u16 b2 = __builtin_bit_cast(u16, (__bf16)p2);
        const u16 b3 = __builtin_bit_cast(u16, (__bf16)p3);
        pk0[q][t] = ((u32)b1 << 16) | b0;
        pk1[q][t] = ((u32)b3 << 16) | b2;
      }
      ps += __shfl_xor(ps, 16);
      ps += __shfl_xor(ps, 32);
      if (skip) {
        lrun[q] += ps;
      } else {
        const float alpha = fast_exp2(mrun[q] - m_new);
        lrun[q] = lrun[q] * alpha + ps;
        mrun[q] = m_new;
        accL[q] *= alpha;
        accH[q] *= alpha;
      }
    }

    // ---- P^T bounce (all q): write [q][i=r][j-words], read B-frags ----
    #pragma unroll
    for (int q = 0; q < 4; ++q)
      #pragma unroll
      for (int t = 0; t < 4; ++t)
        *(u64*)&pbuf[wv][q][r][8*t + 2*g] = ((u64)pk1[q][t] << 32) | pk0[q][t];
    asm volatile("s_waitcnt lgkmcnt(0)" ::: "memory");

    uint4 pr[4][2];
    #pragma unroll
    for (int q = 0; q < 4; ++q)
      #pragma unroll
      for (int c = 0; c < 2; ++c)
        pr[q][c] = *(const uint4*)&pbuf[wv][q][r][16*c + 4*g];
    asm volatile("s_waitcnt lgkmcnt(0)" ::: "memory");
    __builtin_amdgcn_sched_barrier(0);

    // ---- PV: 16 MFMAs ----
    #pragma unroll
    for (int q = 0; q < 4; ++q)
      #pragma unroll
      for (int c = 0; c < 2; ++c) {
        const bf16x8 pf = __builtin_bit_cast(bf16x8, pr[q][c]);
        accL[q] = __builtin_amdgcn_mfma_f32_16x16x32_bf16(vlo[c], pf, accL[q], 0, 0, 0);
        accH[q] = __builtin_amdgcn_mfma_f32_16x16x32_bf16(vhi[c], pf, accH[q], 0, 0, 0);
      }

    buf ^= 1;
  }

  // A^T[d][i] store (unnormalized)
  const size_t obase = ((size_t)(split*8 + bh)) * DIMH * NTOK;
  #pragma unroll
  for (int q = 0; q < 4; ++q) {
    float* ad = Apart + obase + i_base + 16*q + r;
    #pragma unroll
    for (int u = 0; u < 4; ++u) {
      ad[(size_t)(4*g + u) * NTOK]      = accL[q][u];
      ad[(size_t)(16 + 4*g + u) * NTOK] = accH[q][u];
    }
  }
  float* mlb = ml + ((size_t)(split*8 + bh) * 2) * NTOK;
  #pragma unroll
  for (int q = 0; q < 4; ++q) {
    const int i = i_base + 16*q + r;
    if (g == 0) mlb[i]        = mrun[q];
    if (g == 1) mlb[NTOK + i] = lrun[q];
  }
}

// ===================== Kernel B2: split-j combine =====================
template<int NS>
__global__ __launch_bounds__(256)
void attn_combine(const float* __restrict__ Apart, const float* __restrict__ ml,
                  float* __restrict__ ot)
{
  const int bh = blockIdx.x;
  const int i0 = blockIdx.y * 1024 + threadIdx.x * 4;
  f32x4 mv[NS], lv[NS], w[NS];
  #pragma unroll
  for (int s = 0; s < NS; ++s) {
    const float* mlb = ml + ((size_t)(s*8 + bh) * 2) * NTOK;
    mv[s] = *(const f32x4*)(mlb + i0);
    lv[s] = *(const f32x4*)(mlb + NTOK + i0);
  }
  f32x4 inv;
  #pragma unroll
  for (int c = 0; c < 4; ++c) {
    float ms = mv[0][c];
    #pragma unroll
    for (int s = 1; s < NS; ++s) ms = fmaxf(ms, mv[s][c]);
    float lt = 0.f;
    #pragma unroll
    for (int s = 0; s < NS; ++s) {
      const float ww = fast_exp2(mv[s][c] - ms);
      w[s][c] = ww;
      lt += ww * lv[s][c];
    }
    inv[c] = 1.0f / lt;
  }
  #pragma unroll 4
  for (int d = 0; d < 32; ++d) {
    f32x4 acc = {0.f,0.f,0.f,0.f};
    #pragma unroll
    for (int s = 0; s < NS; ++s) {
      const f32x4 a = *(const f32x4*)(Apart + (((size_t)(s*8 + bh)) * DIMH + d) * NTOK + i0);
      acc += w[s] * a;
    }
    acc *= inv;
    *(f32x4*)(ot + ((size_t)bh * DIMH + d) * NTOK + i0) = acc;
  }
}

// ===================== Kernel C: output projection + bias =====================
__global__ __launch_bounds__(256)
void out_proj(const float* __restrict__ ain, const float* __restrict__ w,
              const float* __restrict__ bias, float* __restrict__ out)
{
  __shared__ float xs[128][64];
  __shared__ float wt[128][64];
  const int tid = threadIdx.x;
  const int n0 = blockIdx.x * 64;
  const int o0 = blockIdx.y * 64;
  const int b  = blockIdx.z;

  {
    const float* xb = ain + ((size_t)b * CH) * NTOK + n0;
    const int f4 = tid & 15, c0 = tid >> 4;
    #pragma unroll
    for (int p = 0; p < 8; ++p) {
      const int c = p * 16 + c0;
      *(float4*)&xs[c][f4*4] = *(const float4*)(xb + (size_t)c * NTOK + f4 * 4);
    }
  }
  {
    const int o_l = tid & 63, q4 = tid >> 6;
    const float* wrow = w + (size_t)(o0 + o_l) * CH;
    #pragma unroll
    for (int p = 0; p < 8; ++p) {
      const int c4 = p * 4 + q4;
      const float4 v4 = *(const float4*)(wrow + c4 * 4);
      wt[c4*4+0][o_l] = v4.x;
      wt[c4*4+1][o_l] = v4.y;
      wt[c4*4+2][o_l] = v4.z;
      wt[c4*4+3][o_l] = v4.w;
    }
  }
  __syncthreads();

  const int tx = tid & 15, ty = tid >> 4;
  float acc[4][4] = {};
  for (int c = 0; c < 128; ++c) {
    const float4 xv = *(const float4*)&xs[c][tx*4];
    const float4 wv = *(const float4*)&wt[c][ty*4];
    const float xa[4] = {xv.x, xv.y, xv.z, xv.w};
    const float wa[4] = {wv.x, wv.y, wv.z, wv.w};
    #pragma unroll
    for (int io = 0; io < 4; ++io)
      #pragma unroll
      for (int in = 0; in < 4; ++in)
        acc[io][in] += wa[io] * xa[in];
  }

  #pragma unroll
  for (int io = 0; io < 4; ++io) {
    const int o = o0 + ty*4 + io;
    const float bv = bias[o];
    float4 res = {acc[io][0]+bv, acc[io][1]+bv, acc[io][2]+bv, acc[io][3]+bv};
    *(float4*)(out + ((size_t)b * CH + o) * NTOK + n0 + tx*4) = res;
  }
}

extern "C" void kernel_launch(void* const* d_in, const int* in_sizes, int n_in,
                              void* d_out, int out_size, void* d_ws, size_t ws_size,
                              hipStream_t stream)
{
  const float* x     = (const float*)d_in[0];
  const float* w_qkv = (const float*)d_in[1];
  const float* w_out = (const float*)d_in[2];
  const float* b_out = (const float*)d_in[3];
  float* out = (float*)d_out;

  const size_t MB = 1024 * 1024;
  int nsplit = 1;
  if      (ws_size >= 6*MB + 4*(4*MB + 256*1024)) nsplit = 4;
  else if (ws_size >= 6*MB + 2*(4*MB + 256*1024)) nsplit = 2;

  char* ws = (char*)d_ws;
  bf16_t* qs    = (bf16_t*)(ws);
  bf16_t* ks    = (bf16_t*)(ws + 2*MB);
  bf16_t* vs    = (bf16_t*)(ws + 4*MB);
  float*  Apart = (float*) (ws + 6*MB);
  float*  ml    = (float*) (ws + 6*MB + (size_t)nsplit*4*MB);
  float*  ot    = (float*) (ws);       // overlay on qs+ks (dead after attn)

  qkv_proj<<<dim3(64, 6, 2), 256, 0, stream>>>(x, w_qkv, qs, ks, vs);
  if (nsplit == 4) {
    attn_fwd<16><<<dim3(8, 16, 4), 256, 0, stream>>>(qs, ks, vs, Apart, ml);
    attn_combine<4><<<dim3(8, 4), 256, 0, stream>>>(Apart, ml, ot);
  } else if (nsplit == 2) {
    attn_fwd<32><<<dim3(8, 16, 2), 256, 0, stream>>>(qs, ks, vs, Apart, ml);
    attn_combine<2><<<dim3(8, 4), 256, 0, stream>>>(Apart, ml, ot);
  } else {
    attn_fwd<64><<<dim3(8, 16, 1), 256, 0, stream>>>(qs, ks, vs, Apart, ml);
    attn_combine<1><<<dim3(8, 4), 256, 0, stream>>>(Apart, ml, ot);
  }
  out_proj<<<dim3(64, 2, 2), 256, 0, stream>>>(ot, w_out, b_out, out);
}

// Round 5
// 73.490 us; speedup vs baseline: 1.8200x; 1.8200x over previous
//
#include <hip/hip_runtime.h>
#include <hip/hip_bf16.h>

typedef __bf16 bf16_t;
typedef __bf16 bf16x8 __attribute__((ext_vector_type(8)));
typedef float f32x4 __attribute__((ext_vector_type(4)));
typedef unsigned short u16;
typedef unsigned int u32;
typedef unsigned long long u64;

#define CH    128
#define NTOK  4096
#define DIMH  32

__device__ __forceinline__ float fast_exp2(float x) {
#if __has_builtin(__builtin_amdgcn_exp2f)
  return __builtin_amdgcn_exp2f(x);
#else
  return exp2f(x);
#endif
}

// ===================== Kernel A: QKV projection =====================
// x: [B][128][4096] f32, w: [384][128] f32.
// qs/ks: [bh][n][32] bf16 (q pre-scaled by 32^-0.5*log2e).
// vs: TILED+SWIZZLED [bh][jb][32 d][64 j] bf16, 16B-chunk index within each
//     128B d-row XORed with (d&7) so attention's LDS V-frag reads are
//     bank-conflict-free.
__global__ __launch_bounds__(256)
void qkv_proj(const float* __restrict__ x, const float* __restrict__ w,
              bf16_t* __restrict__ qs, bf16_t* __restrict__ ks, bf16_t* __restrict__ vs)
{
  __shared__ float xs[128][64];
  __shared__ float wt[128][64];
  const int tid = threadIdx.x;
  const int n0 = blockIdx.x * 64;
  const int o0 = blockIdx.y * 64;
  const int b  = blockIdx.z;

  { // stage x tile [128 c][64 n] via float4 (coalesced)
    const float* xb = x + ((size_t)b * CH) * NTOK + n0;
    const int f4 = tid & 15, c0 = tid >> 4;
    #pragma unroll
    for (int p = 0; p < 8; ++p) {
      const int c = p * 16 + c0;
      *(float4*)&xs[c][f4 * 4] = *(const float4*)(xb + (size_t)c * NTOK + f4 * 4);
    }
  }
  { // stage w tile transposed: wt[c][o_local]
    const int o_l = tid & 63, q4 = tid >> 6;
    const float* wrow = w + (size_t)(o0 + o_l) * CH;
    #pragma unroll
    for (int p = 0; p < 8; ++p) {
      const int c4 = p * 4 + q4;
      const float4 v4 = *(const float4*)(wrow + c4 * 4);
      wt[c4*4+0][o_l] = v4.x;
      wt[c4*4+1][o_l] = v4.y;
      wt[c4*4+2][o_l] = v4.z;
      wt[c4*4+3][o_l] = v4.w;
    }
  }
  __syncthreads();

  const int tx = tid & 15, ty = tid >> 4;
  float acc[4][4] = {};
  for (int c = 0; c < 128; ++c) {
    const float4 xv = *(const float4*)&xs[c][tx * 4];
    const float4 wv = *(const float4*)&wt[c][ty * 4];
    const float xa[4] = {xv.x, xv.y, xv.z, xv.w};
    const float wa[4] = {wv.x, wv.y, wv.z, wv.w};
    #pragma unroll
    for (int io = 0; io < 4; ++io)
      #pragma unroll
      for (int in = 0; in < 4; ++in)
        acc[io][in] += wa[io] * xa[in];
  }
  __syncthreads();

  float (*out_s)[65] = (float(*)[65])&xs[0][0];
  #pragma unroll
  for (int io = 0; io < 4; ++io)
    #pragma unroll
    for (int in = 0; in < 4; ++in)
      out_s[ty*4+io][tx*4+in] = acc[io][in];
  __syncthreads();

  const float QSCALE = 0.17677669529663687f * 1.4426950408889634f; // 32^-0.5 * log2(e)
  if (o0 < 256) {
    bf16_t* dst = (o0 < 128) ? qs : ks;
    const float mul = (o0 < 128) ? QSCALE : 1.0f;
    const int obase = o0 & 127;
    #pragma unroll
    for (int p = 0; p < 16; ++p) {
      const int n_l = p * 4 + (tid >> 6);
      const int o_l = tid & 63;
      const int o = obase + o_l;
      const int h = o >> 5, d = o & 31;
      dst[(((size_t)(b*4 + h)) * NTOK + n0 + n_l) * DIMH + d] = (bf16_t)(out_s[o_l][n_l] * mul);
    }
  } else {
    // v tiled+swizzled: tile (b*4+h, jb=n0/64); elem = d*64 + ((jc^(d&7))*8 + e)
    const int obase = o0 - 256;
    const int jb = n0 >> 6;
    #pragma unroll
    for (int p = 0; p < 16; ++p) {
      const int o_l = p * 4 + (tid >> 6);
      const int n_l = tid & 63;
      const int o = obase + o_l;
      const int h = o >> 5, d = o & 31;
      const int jc = n_l >> 3, e = n_l & 7;
      const size_t tilebase = ((size_t)(b*4 + h) * 64 + jb) * 2048;
      vs[tilebase + d*64 + ((jc ^ (d & 7)) * 8) + e] = (bf16_t)out_s[o_l][n_l];
    }
  }
}

// helper: stage one 4KB K-tile + 4KB V-tile into LDS (direct-to-LDS)
__device__ __forceinline__ void stage_tile(const char* kg, const char* vg,
                                           char* lds, int tid)
{
#if __has_builtin(__builtin_amdgcn_global_load_lds)
  __builtin_amdgcn_global_load_lds(
      (const __attribute__((address_space(1))) void*)(kg + tid * 16),
      (__attribute__((address_space(3))) void*)(lds + tid * 16), 16, 0, 0);
  __builtin_amdgcn_global_load_lds(
      (const __attribute__((address_space(1))) void*)(vg + tid * 16),
      (__attribute__((address_space(3))) void*)(lds + 4096 + tid * 16), 16, 0, 0);
#else
  const uint4 a = *(const uint4*)(kg + tid * 16);
  const uint4 b = *(const uint4*)(vg + tid * 16);
  *(uint4*)(lds + tid * 16) = a;
  *(uint4*)(lds + 4096 + tid * 16) = b;
#endif
}

// ===================== Kernel B: flash attention (LDS K/V, in-register P route) =====================
// Block: 4 waves x 64 i = 256 i-rows; per j-iter the block stages the next
// 64j K-tile + V-tile into an LDS double buffer (global_load_lds, counted by
// the single per-iter vmcnt(0)+barrier). Per wave, per q-subtile:
//   S^T = mfma(K, Q_q) -> online softmax (defer-max THR=8) ->
//   P redistribution fully IN-REGISTER: v_cvt_pk_bf16_f32 pairs, then
//   v_permlane32_swap + v_permlane16_swap route word Jp=(b4 b3 b2 b1 b0) from
//   lane-group (b2,b1) to (b3,b2) -> PV: O^T += mfma(V^T, P).
// No P LDS buffer, no lgkmcnt(0) drains -> LDS=16KB, 4 blocks/CU at 128 VGPR.
template<int JB_PER>
__global__ __launch_bounds__(256, 4)
void attn_fwd(const bf16_t* __restrict__ qs, const bf16_t* __restrict__ ks,
              const bf16_t* __restrict__ vs, float* __restrict__ Apart,
              float* __restrict__ ml)
{
  __shared__ alignas(16) char kvbuf[2][8192];          // [buf][K 4KB | V 4KB]

  const int bh    = blockIdx.x;   // 0..7 (fastest dim -> one head per XCD)
  const int ic    = blockIdx.y;   // 0..15
  const int split = blockIdx.z;
  const int tid   = threadIdx.x;
  const int wv    = tid >> 6;
  const int lane  = tid & 63;
  const int g = lane >> 4, r = lane & 15;
  const int i_base = ic * 256 + wv * 64;

  const bf16_t* qh = qs + (size_t)bh * NTOK * DIMH;
  const char*   kg = (const char*)(ks + (size_t)bh * NTOK * DIMH);
  const char*   vg = (const char*)(vs + (size_t)bh * NTOK * DIMH);

  // Q B-frags (hoisted): col=i (lane&15), k=d ((lane>>4)*8+e)
  bf16x8 qf[4];
  #pragma unroll
  for (int q = 0; q < 4; ++q)
    qf[q] = *(const bf16x8*)(qh + (size_t)(i_base + 16*q + r) * DIMH + g * 8);

  f32x4 accL[4] = {}, accH[4] = {};
  const f32x4 zero = {0.f, 0.f, 0.f, 0.f};
  float mrun[4] = {-3.0e38f, -3.0e38f, -3.0e38f, -3.0e38f};
  float lrun[4] = {0.f, 0.f, 0.f, 0.f};

  const int jb0 = split * JB_PER;
  stage_tile(kg + (size_t)jb0 * 4096, vg + (size_t)jb0 * 4096, kvbuf[0], tid);

  for (int it = 0; it < JB_PER; ++it) {
    // staged data for buf[it&1] ready; all waves consumed their prev-iter frags
    asm volatile("s_waitcnt vmcnt(0)" ::: "memory");
    __builtin_amdgcn_s_barrier();

    if (it + 1 < JB_PER) {
      const size_t off = (size_t)(jb0 + it + 1) * 4096;
      stage_tile(kg + off, vg + off, kvbuf[(it + 1) & 1], tid);
    }

    const char* kb = kvbuf[it & 1];
    const char* vb = kb + 4096;

    // ---- LDS -> frag reads (conflict-free patterns) ----
    bf16x8 kf[4], vlo[2], vhi[2];
    #pragma unroll
    for (int t = 0; t < 4; ++t)
      kf[t] = __builtin_bit_cast(bf16x8, *(const uint4*)(kb + (16*t + r) * 64 + g * 16));
    #pragma unroll
    for (int c = 0; c < 2; ++c) {
      const int swz = ((4*c + g) ^ (r & 7)) * 16;
      vlo[c] = __builtin_bit_cast(bf16x8, *(const uint4*)(vb + r * 128 + swz));
      vhi[c] = __builtin_bit_cast(bf16x8, *(const uint4*)(vb + (16 + r) * 128 + swz));
    }

    #pragma unroll
    for (int q = 0; q < 4; ++q) {
      // ---- QK^T: st[t] = S^T[j=16t+4g+u][i=i_base+16q+r] ----
      f32x4 st[4];
      #pragma unroll
      for (int t = 0; t < 4; ++t)
        st[t] = __builtin_amdgcn_mfma_f32_16x16x32_bf16(kf[t], qf[q], zero, 0, 0, 0);

      // ---- online softmax (16 values per lane, all for ONE i) ----
      float m = -3.0e38f;
      #pragma unroll
      for (int t = 0; t < 4; ++t)
        m = fmaxf(m, fmaxf(fmaxf(st[t][0], st[t][1]), fmaxf(st[t][2], st[t][3])));
      m = fmaxf(m, __shfl_xor(m, 16));
      m = fmaxf(m, __shfl_xor(m, 32));

      const bool skip = __all(m - mrun[q] <= 8.0f);
      const float m_new = skip ? mrun[q] : fmaxf(mrun[q], m);

      float ps = 0.f;
      u32 wpk[4][2];
      #pragma unroll
      for (int t = 0; t < 4; ++t) {
        const float p0 = fast_exp2(st[t][0] - m_new);
        const float p1 = fast_exp2(st[t][1] - m_new);
        const float p2 = fast_exp2(st[t][2] - m_new);
        const float p3 = fast_exp2(st[t][3] - m_new);
        ps += (p0 + p1) + (p2 + p3);
        asm("v_cvt_pk_bf16_f32 %0, %1, %2" : "=v"(wpk[t][0]) : "v"(p0), "v"(p1));
        asm("v_cvt_pk_bf16_f32 %0, %1, %2" : "=v"(wpk[t][1]) : "v"(p2), "v"(p3));
      }
      ps += __shfl_xor(ps, 16);
      ps += __shfl_xor(ps, 32);
      if (skip) {
        lrun[q] += ps;
      } else {
        const float alpha = fast_exp2(mrun[q] - m_new);
        lrun[q] = lrun[q] * alpha + ps;
        mrun[q] = m_new;
        accL[q] *= alpha;
        accH[q] *= alpha;
      }

      // ---- in-register P^T -> B-frag route (T12 + gfx950 permlane swaps) ----
      // word Jp: bits (b4 b3 b2 b1 b0); source lane-group (b2,b1), reg t=(b4,b3),
      // v=b0; target lane-group (b3,b2), frag c=b4, word slot widx=(b1,b0).
      uint4 pr[2];
      #pragma unroll
      for (int c = 0; c < 2; ++c) {
        #pragma unroll
        for (int v = 0; v < 2; ++v) {
          u32 a = wpk[2*c + 0][v];   // b3 = 0
          u32 b = wpk[2*c + 1][v];   // b3 = 1
          asm("v_permlane32_swap_b32 %0, %1" : "+v"(a), "+v"(b));
          asm("v_permlane16_swap_b32 %0, %1" : "+v"(a), "+v"(b));
          pr[c][0 + v] = a;   // widx = (b1=0, v)
          pr[c][2 + v] = b;   // widx = (b1=1, v)
        }
      }

      // ---- PV: O^T += mfma(V^T, P) ----
      #pragma unroll
      for (int c = 0; c < 2; ++c) {
        const bf16x8 pf = __builtin_bit_cast(bf16x8, pr[c]);
        accL[q] = __builtin_amdgcn_mfma_f32_16x16x32_bf16(vlo[c], pf, accL[q], 0, 0, 0);
        accH[q] = __builtin_amdgcn_mfma_f32_16x16x32_bf16(vhi[c], pf, accH[q], 0, 0, 0);
      }
    }
  }

  // A^T[d][i] store (unnormalized)
  const size_t obase = ((size_t)(split*8 + bh)) * DIMH * NTOK;
  #pragma unroll
  for (int q = 0; q < 4; ++q) {
    float* ad = Apart + obase + i_base + 16*q + r;
    #pragma unroll
    for (int u = 0; u < 4; ++u) {
      ad[(size_t)(4*g + u) * NTOK]      = accL[q][u];
      ad[(size_t)(16 + 4*g + u) * NTOK] = accH[q][u];
    }
  }
  float* mlb = ml + ((size_t)(split*8 + bh) * 2) * NTOK;
  #pragma unroll
  for (int q = 0; q < 4; ++q) {
    const int i = i_base + 16*q + r;
    if (g == 0) mlb[i]        = mrun[q];
    if (g == 1) mlb[NTOK + i] = lrun[q];
  }
}

// ===================== Kernel C: fused split-combine + output projection =====================
// xs[c][n] = inv(h,n) * sum_s w_s(h,n) * Apart[s][bh][d][n]   (c = h*32+d)
// then out[b][o][n] = sum_c w_out[o][c]*xs[c][n] + bias[o]
template<int NS>
__global__ __launch_bounds__(256)
void out_proj_combine(const float* __restrict__ Apart, const float* __restrict__ ml,
                      const float* __restrict__ w, const float* __restrict__ bias,
                      float* __restrict__ out)
{
  __shared__ float xs[128][64];
  __shared__ float wt[128][64];
  __shared__ alignas(16) float wls[4][NS][64];
  const int tid = threadIdx.x;
  const int n0 = blockIdx.x * 64;
  const int o0 = blockIdx.y * 64;
  const int b  = blockIdx.z;

  { // combine weights: thread -> (h = tid>>6, n = tid&63)
    const int h = tid >> 6, n_l = tid & 63;
    const int bh = b*4 + h;
    float m[NS], l[NS], wv[NS];
    #pragma unroll
    for (int s = 0; s < NS; ++s) {
      const float* mlb = ml + ((size_t)(s*8 + bh) * 2) * NTOK;
      m[s] = mlb[n0 + n_l];
      l[s] = mlb[NTOK + n0 + n_l];
    }
    float mx = m[0];
    #pragma unroll
    for (int s = 1; s < NS; ++s) mx = fmaxf(mx, m[s]);
    float L = 0.f;
    #pragma unroll
    for (int s = 0; s < NS; ++s) { wv[s] = fast_exp2(m[s] - mx); L += wv[s] * l[s]; }
    const float inv = 1.0f / L;
    #pragma unroll
    for (int s = 0; s < NS; ++s) wls[h][s][n_l] = wv[s] * inv;
  }
  { // stage w tile transposed: wt[c][o_local]
    const int o_l = tid & 63, q4 = tid >> 6;
    const float* wrow = w + (size_t)(o0 + o_l) * CH;
    #pragma unroll
    for (int p = 0; p < 8; ++p) {
      const int c4 = p * 4 + q4;
      const float4 v4 = *(const float4*)(wrow + c4 * 4);
      wt[c4*4+0][o_l] = v4.x;
      wt[c4*4+1][o_l] = v4.y;
      wt[c4*4+2][o_l] = v4.z;
      wt[c4*4+3][o_l] = v4.w;
    }
  }
  __syncthreads();

  { // stage combined x tile [128 c][64 n]
    const int f4 = tid & 15, c0 = tid >> 4;
    #pragma unroll
    for (int p = 0; p < 8; ++p) {
      const int c = p * 16 + c0;
      const int h = c >> 5, d = c & 31;
      f32x4 acc = {0.f, 0.f, 0.f, 0.f};
      #pragma unroll
      for (int s = 0; s < NS; ++s) {
        const f32x4 a = *(const f32x4*)(Apart +
            ((size_t)((s*8 + b*4 + h) * DIMH + d)) * NTOK + n0 + f4 * 4);
        const f32x4 ww = *(const f32x4*)&wls[h][s][f4 * 4];
        acc += a * ww;
      }
      *(f32x4*)&xs[c][f4 * 4] = acc;
    }
  }
  __syncthreads();

  const int tx = tid & 15, ty = tid >> 4;
  float acc[4][4] = {};
  for (int c = 0; c < 128; ++c) {
    const float4 xv = *(const float4*)&xs[c][tx*4];
    const float4 wv = *(const float4*)&wt[c][ty*4];
    const float xa[4] = {xv.x, xv.y, xv.z, xv.w};
    const float wa[4] = {wv.x, wv.y, wv.z, wv.w};
    #pragma unroll
    for (int io = 0; io < 4; ++io)
      #pragma unroll
      for (int in = 0; in < 4; ++in)
        acc[io][in] += wa[io] * xa[in];
  }

  #pragma unroll
  for (int io = 0; io < 4; ++io) {
    const int o = o0 + ty*4 + io;
    const float bv = bias[o];
    float4 res = {acc[io][0]+bv, acc[io][1]+bv, acc[io][2]+bv, acc[io][3]+bv};
    *(float4*)(out + ((size_t)b * CH + o) * NTOK + n0 + tx*4) = res;
  }
}

extern "C" void kernel_launch(void* const* d_in, const int* in_sizes, int n_in,
                              void* d_out, int out_size, void* d_ws, size_t ws_size,
                              hipStream_t stream)
{
  const float* x     = (const float*)d_in[0];
  const float* w_qkv = (const float*)d_in[1];
  const float* w_out = (const float*)d_in[2];
  const float* b_out = (const float*)d_in[3];
  float* out = (float*)d_out;

  const size_t MB = 1024 * 1024;
  const size_t KB = 1024;
  // need: 6MB (qkv) + nsplit*(4MB Apart + 256KB ml)
  int nsplit = 1;
  if      (ws_size >= 6*MB + 8*(4*MB + 256*KB)) nsplit = 8;
  else if (ws_size >= 6*MB + 4*(4*MB + 256*KB)) nsplit = 4;
  else if (ws_size >= 6*MB + 2*(4*MB + 256*KB)) nsplit = 2;

  char* ws = (char*)d_ws;
  bf16_t* qs    = (bf16_t*)(ws);
  bf16_t* ks    = (bf16_t*)(ws + 2*MB);
  bf16_t* vs    = (bf16_t*)(ws + 4*MB);
  float*  Apart = (float*) (ws + 6*MB);
  float*  ml    = (float*) (ws + 6*MB + (size_t)nsplit*4*MB);

  qkv_proj<<<dim3(64, 6, 2), 256, 0, stream>>>(x, w_qkv, qs, ks, vs);
  if (nsplit == 8) {
    attn_fwd<8><<<dim3(8, 16, 8), 256, 0, stream>>>(qs, ks, vs, Apart, ml);
    out_proj_combine<8><<<dim3(64, 2, 2), 256, 0, stream>>>(Apart, ml, w_out, b_out, out);
  } else if (nsplit == 4) {
    attn_fwd<16><<<dim3(8, 16, 4), 256, 0, stream>>>(qs, ks, vs, Apart, ml);
    out_proj_combine<4><<<dim3(64, 2, 2), 256, 0, stream>>>(Apart, ml, w_out, b_out, out);
  } else if (nsplit == 2) {
    attn_fwd<32><<<dim3(8, 16, 2), 256, 0, stream>>>(qs, ks, vs, Apart, ml);
    out_proj_combine<2><<<dim3(64, 2, 2), 256, 0, stream>>>(Apart, ml, w_out, b_out, out);
  } else {
    attn_fwd<64><<<dim3(8, 16, 1), 256, 0, stream>>>(qs, ks, vs, Apart, ml);
    out_proj_combine<1><<<dim3(64, 2, 2), 256, 0, stream>>>(Apart, ml, w_out, b_out, out);
  }
}